// Round 2
// baseline (636.775 us; speedup 1.0000x reference)
//
#include <hip/hip_runtime.h>

// NeighborSample: x[8,64,64,192] f32 -> out[8*64*64, 5, 5, 192] f32
//
// R6: R5 (LDS-staged gather, linear output sweep) + two fixes aimed at the
// measured 2.85 TB/s plateau (vs 6.2 TB/s for the harness's pure fill):
//
//  1. XCD-bijective block swizzle: blk = (phys%8)*256 + phys/8. With 2048
//     blocks this gives each of the 8 XCDs exactly one image b (256 blocks).
//     All halo reuse (y-adjacent blocks share 80% of their staged window)
//     becomes XCD-local; the per-XCD input slice is 3 MB < 4 MB L2, so
//     staging reads become L2 hits and HBM sees an almost pure write
//     stream -> no read/write bus turnaround penalty.
//  2. Nontemporal output stores (__builtin_nontemporal_store): the output
//     is written once and never read by us; nt bypasses L2 write-allocate/
//     evict churn on the 629 MB stream (per-XCD L2 is only 4 MB).
//
// R4 vs R5 showed write *ordering* is irrelevant (226 vs 229 us); this
// round tests the read-mixing and L2-write-path theories.

typedef float f32x4 __attribute__((ext_vector_type(4)));

constexpr int B = 8;
constexpr int H = 64;
constexpr int W = 64;
constexpr int C4 = 48;               // 192 ch / 4 = float4 per pixel-channel row
constexpr int K = 5;
constexpr int PAD = K / 2;
constexpr int ROW = K * K * C4;      // 1200 float4 per output pixel

constexpr int TP   = 16;             // x-consecutive pixels per block
constexpr int WIN  = TP + 2 * PAD;   // 20 staged input cols
constexpr int WROW = WIN * C4;       // 960 float4 per staged row
constexpr int LDSF4 = K * WROW;      // 4800 float4 = 76,800 B LDS (2 blk/CU)
constexpr int OUTF4 = TP * ROW;      // 19200 float4 output per block

constexpr int BLOCK = 256;
constexpr unsigned NBLK = (unsigned)B * H * (W / TP);   // 2048 blocks
constexpr unsigned NXCD = 8;
constexpr unsigned CPX  = NBLK / NXCD;                  // 256 blocks per XCD

__global__ __launch_bounds__(BLOCK) void neighbor_lds_kernel(
    const f32x4* __restrict__ in, f32x4* __restrict__ out) {
  __shared__ f32x4 lds[LDSF4];

  const int tid = (int)threadIdx.x;

  // XCD-bijective swizzle: dispatch round-robins phys%8 across XCDs, so
  // logical blocks [k*256,(k+1)*256) — i.e. image b=k — all land on XCD k.
  const unsigned phys = blockIdx.x;
  const unsigned blk  = (phys & (NXCD - 1)) * CPX + (phys >> 3);

  const int xblk = (int)(blk & (W / TP - 1));   // 4 x-blocks per row
  const int y    = (int)((blk >> 2) & (H - 1));
  const int b    = (int)(blk >> 8);
  const int x0   = xblk * TP;

  // ---- stage [5][WIN][C4] halo window into LDS (zero-padded) ----
  const bool interior =
      (y >= PAD) & (y < H - PAD) & (x0 >= PAD) & (x0 + TP + PAD <= W);

  if (interior) {
    // Window rows are contiguous 960-f4 runs in global memory; every wave's
    // 64 lanes read one contiguous, aligned 1 KB chunk.
    const f32x4* src = in + ((b * H + (y - PAD)) * W + (x0 - PAD)) * C4;
    for (int i = tid; i < LDSF4; i += BLOCK) {
      int r   = i / WROW;
      int rem = i - r * WROW;
      lds[i] = src[r * (W * C4) + rem];
    }
  } else {
    for (int i = tid; i < LDSF4; i += BLOCK) {
      int r   = i / WROW;
      int rem = i - r * WROW;
      int col = rem / C4;
      int k4  = rem - col * C4;
      int ys = y + r - PAD;
      int xs = x0 + col - PAD;
      f32x4 v = {0.f, 0.f, 0.f, 0.f};
      if ((unsigned)ys < (unsigned)H && (unsigned)xs < (unsigned)W)
        v = in[((b * H + ys) * W + xs) * C4 + k4];
      lds[i] = v;
    }
  }
  __syncthreads();

  // ---- linear write sweep: one contiguous 307 KB stream per block ----
  f32x4* dst = out + (size_t)((b * H + y) * W + x0) * ROW;

  // Decompose j = pl*1200 + tap*48 + k4; maintained incrementally
  // (j += 256  <=>  k4 += 16, tap += 5, with carries).  tid < 256 => pl0 = 0.
  int tap = tid / C4;
  int k4  = tid - tap * C4;
  int pl  = 0;

#pragma unroll 5
  for (int j = tid; j < OUTF4; j += BLOCK) {
    int oi = (tap * 205) >> 10;        // tap / 5  (exact for tap in [0,25))
    int oj = tap - oi * 5;
    __builtin_nontemporal_store(lds[(oi * WIN + pl + oj) * C4 + k4], &dst[j]);
    k4  += BLOCK % C4;                 // +16
    tap += BLOCK / C4;                 // +5
    if (k4 >= C4)   { k4 -= C4; ++tap; }
    if (tap >= K*K) { tap -= K*K; ++pl; }
  }
}

extern "C" void kernel_launch(void* const* d_in, const int* in_sizes, int n_in,
                              void* d_out, int out_size, void* d_ws, size_t ws_size,
                              hipStream_t stream) {
  const f32x4* in = (const f32x4*)d_in[0];
  f32x4* out = (f32x4*)d_out;
  neighbor_lds_kernel<<<NBLK, BLOCK, 0, stream>>>(in, out);
}